// Round 19
// baseline (105.303 us; speedup 1.0000x reference)
//
#include <hip/hip_runtime.h>
#include <hip/hip_bf16.h>

typedef unsigned short u16;
typedef unsigned short ushort8v __attribute__((ext_vector_type(8)));
typedef __bf16 bf16x8 __attribute__((ext_vector_type(8)));
typedef float f32x4 __attribute__((ext_vector_type(4)));

#define NB 16   // batch
#define NK 32   // K slices
#define ND 256  // D
#define NL 256  // L1 == L2

__device__ __forceinline__ u16 f2bf(float f) {
    __hip_bfloat16 h = __float2bfloat16(f);
    return __builtin_bit_cast(u16, h);
}

// async global->LDS, 16B per lane; lds dst = wave-uniform base + lane*16
__device__ __forceinline__ void gload_lds16(const void* g, void* l) {
    __builtin_amdgcn_global_load_lds(
        (const __attribute__((address_space(1))) unsigned int*)g,
        (__attribute__((address_space(3))) unsigned int*)l, 16, 0, 0);
}

// lgkm-only barrier: orders LDS traffic across waves WITHOUT draining vmcnt
// (epilogue's global stores stay in flight across it)
__device__ __forceinline__ void barrier_lgkm() {
    asm volatile("s_waitcnt lgkmcnt(0)" ::: "memory");
    __builtin_amdgcn_s_barrier();
    asm volatile("" ::: "memory");
}

// Fragment-order layout for a 256x256 matrix X[r][c] (c = contraction dim):
//   buf[((rt*8 + ct)*64 + lane)*8 + (c&7)], rt=r>>4, ct=c>>5,
//   lane = (r&15) | (((c>>3)&3)<<4)
// => a wave's 16x16x32 MFMA fragment is 1 KiB contiguous; coalesced dwordx4 loads.

// ---------------- prep (identical to R18) ----------------
__global__ void prep_kernel(const float* __restrict__ x1, const float* __restrict__ x2,
                            const float* __restrict__ W,
                            u16* __restrict__ x1f, u16* __restrict__ x2f, u16* __restrict__ Wtf) {
    __shared__ float xs[32 * 260];
    int bid = blockIdx.x;
    int tid = threadIdx.x;
    if (bid < 2048) {
        const float* src; u16* dst; long f4;
        if (bid < 1024) { src = x1; dst = x1f; f4 = (long)bid * 256 + tid; }
        else            { src = x2; dst = x2f; f4 = (long)(bid - 1024) * 256 + tid; }
        long idx = f4 << 2;
        int mat = (int)(idx >> 16);
        int r = (int)((idx >> 8) & 255);
        int c = (int)(idx & 255);
        float4 v = ((const float4*)src)[f4];
        ushort4 o;
        o.x = f2bf(v.x); o.y = f2bf(v.y); o.z = f2bf(v.z); o.w = f2bf(v.w);
        int rt = r >> 4, ct = c >> 5;
        int lane = (r & 15) | (((c >> 3) & 3) << 4);
        long off = ((long)mat << 16) + (((rt << 3) + ct) << 9) + (lane << 3) + (c & 7);
        *(ushort4*)(dst + off) = o;
        return;
    }
    int wb = bid - 2048;
    int k  = wb >> 3;
    int dg = wb & 7;
    const float* wsrc = W + ((long)k << 16) + ((long)dg << 13);
#pragma unroll
    for (int it = 0; it < 8; ++it) {
        int ch = (it << 8) + tid;
        int row = ch >> 6;
        int col4 = ch & 63;
        float4 v = *(const float4*)(wsrc + (row << 8) + (col4 << 2));
        *(float4*)(xs + row * 260 + (col4 << 2)) = v;
    }
    __syncthreads();
    int e = tid;
    int rt = e >> 4;
    u16* wdst = Wtf + ((long)k << 16) + ((long)((rt << 3) + dg) << 9);
#pragma unroll
    for (int g = 0; g < 4; ++g) {
        ushort8v pk;
#pragma unroll
        for (int q = 0; q < 8; ++q)
            pk[q] = f2bf(xs[((g << 3) + q) * 260 + e]);
        *(ushort8v*)(wdst + (((e & 15) | (g << 4)) << 3)) = pk;
    }
}

// ---------------- main: 4-k loop, l-split, full-row stores, pipelined ----------------
// grid: 512 = (kg 8) x (b 16) x (lq 4); XCD x owns kg-pair (x>>1), b-octet (x&1):
//       2kg x 8b x 4lq = 64 blocks/XCD; L2 footprint 1MB W + 1MB x1 + 1MB x2 = 3MB.
// LDS: ldsA = x1 quarter (32 KiB, persistent over all 4 k); ldsT = T' bf16 swz /
//      epilogue f32 chunks (32 KiB, per-k); r1s[4][64] upfront.
// per k: pipelined A (Wt global + x1 LDS) -> lgkm-bar -> T' write (+V2 fold) ->
//        lgkm-bar -> pipelined B (x2 global + T' LDS) -> lgkm-bar -> epilogue
//        (+r1, relu, FULL 1KB-row stores, lgkm-only barriers). Stores stay in
//        flight and drain progressively under next k's phase-A MFMAs.
__launch_bounds__(512, 4)
__global__ void ntn_main(const u16* __restrict__ x1f, const u16* __restrict__ x2f,
                         const u16* __restrict__ Wtf,
                         const float* __restrict__ V, const float* __restrict__ bb,
                         float* __restrict__ out) {
    __shared__ __align__(16) char ldsA[32768];   // x1 quarter (persistent)
    __shared__ __align__(16) char ldsT[32768];   // T' bf16 -> epilogue f32 chunks
    __shared__ float r1s[4][64];                 // lin1+b per k, per l

    // supertile decode (bijective over 512): xcd = bid&7 -> (kg-pair, b-octet)
    int bid = blockIdx.x;
    int xcd = bid & 7;
    int i   = bid >> 3;                      // 0..63 within XCD
    int kg  = ((xcd >> 1) << 1) | (i >> 5);  // 0..7 (4 k per block)
    int b   = ((xcd & 1) << 3) | ((i >> 2) & 7);
    int lq  = i & 3;

    int tid  = threadIdx.x;
    int lane = tid & 63;
    int wid  = tid >> 6;
    int wm = wid >> 1;             // m/e-group 0..3
    int wl = wid & 1;              // l-group 0..1
    int lrow = lane & 15;
    int j4   = (lane >> 4) << 2;
    int lk8  = (lane >> 4) << 3;

    const u16* x2p = x2f + ((long)b << 16);

    // ---- stage x1 l-quarter once (async, 32 chunks of 1 KiB)
    {
        const char* src = (const char*)(x1f + ((long)b << 16) + ((long)lq << 14));
#pragma unroll
        for (int it = 0; it < 4; ++it) {
            int chunk = (it << 3) + wid;
            gload_lds16(src + (chunk << 10) + (lane << 4), ldsA + (chunk << 10));
        }
    }
    __syncthreads();   // x1 staged

    // ---- r1s[ki][l] = x1[l].V1[k] + b[k] for all 4 k (8 threads per l)
    {
        int ll = tid >> 3;
        int et8 = tid & 7;
#pragma unroll
        for (int ki = 0; ki < 4; ++ki) {
            int kk = (kg << 2) + ki;
            const float* v1p = V + ((long)kk << 9) + (et8 << 5);
            float s = 0.f;
#pragma unroll
            for (int eg = 0; eg < 4; ++eg) {
                int lp = (ll & 15) | (eg << 4);
                bf16x8 xv = *(const bf16x8*)(ldsA + ((((ll >> 4) << 3) + et8) << 10) + (lp << 4));
                float4 va = *(const float4*)(v1p + (eg << 3));
                float4 vb = *(const float4*)(v1p + (eg << 3) + 4);
                s += (float)xv[0] * va.x + (float)xv[1] * va.y + (float)xv[2] * va.z + (float)xv[3] * va.w
                   + (float)xv[4] * vb.x + (float)xv[5] * vb.y + (float)xv[6] * vb.z + (float)xv[7] * vb.w;
            }
            s += __shfl_xor(s, 1);
            s += __shfl_xor(s, 2);
            s += __shfl_xor(s, 4);
            if ((tid & 7) == 0) r1s[ki][ll] = s + bb[kk];
        }
    }
    // r1s visibility to all waves is covered by the barriers before first epilogue.

    const f32x4 fz = {0.f, 0.f, 0.f, 0.f};

    for (int ki = 0; ki < 4; ++ki) {
        int k = (kg << 2) + ki;
        const u16* wtp = Wtf + ((long)k << 16);

        // ================= phase A: T' = x1q @ W[k]  (M=e, N=l, K=d), pipelined ======
        f32x4 acc[4][2];
#pragma unroll
        for (int q = 0; q < 4; ++q) { acc[q][0] = fz; acc[q][1] = fz; }
        {
            bf16x8 afC[4], afN[4], bflC[2], bflN[2];
#pragma unroll
            for (int q = 0; q < 4; ++q)
                afC[q] = *(const bf16x8*)(wtp + ((((wm << 2) + q) << 3) << 9) + (lane << 3));
#pragma unroll
            for (int p = 0; p < 2; ++p)
                bflC[p] = *(const bf16x8*)(ldsA + (((((wl << 1) + p) << 3) << 10) + (lane << 4)));
#pragma unroll
            for (int dt = 0; dt < 8; ++dt) {
                if (dt < 7) {
#pragma unroll
                    for (int q = 0; q < 4; ++q)
                        afN[q] = *(const bf16x8*)(wtp + (((((wm << 2) + q) << 3) + dt + 1) << 9) + (lane << 3));
#pragma unroll
                    for (int p = 0; p < 2; ++p)
                        bflN[p] = *(const bf16x8*)(ldsA + ((((((wl << 1) + p) << 3) + dt + 1) << 10) + (lane << 4)));
                }
#pragma unroll
                for (int p = 0; p < 2; ++p)
#pragma unroll
                    for (int q = 0; q < 4; ++q)
                        acc[q][p] = __builtin_amdgcn_mfma_f32_16x16x32_bf16(afC[q], bflC[p], acc[q][p], 0, 0, 0);
#pragma unroll
                for (int q = 0; q < 4; ++q) afC[q] = afN[q];
#pragma unroll
                for (int p = 0; p < 2; ++p) bflC[p] = bflN[p];
            }
        }
        barrier_lgkm();   // prev k's epilogue stream (ds_reads) done -> ldsT reusable

        // ---- write T'[l 64][e 256] bf16 swizzled; V2[e] added in f32 (lin2 fold)
        {
            const float* v2base = V + ((long)k << 9) + 256;
#pragma unroll
            for (int q = 0; q < 4; ++q) {
                int e0 = (wm << 6) + (q << 4) + j4;
                float4 v2q = *(const float4*)(v2base + e0);
#pragma unroll
                for (int p = 0; p < 2; ++p) {
                    int l = (wl << 5) + (p << 4) + lrow;
                    ushort4 pk;
                    pk.x = f2bf(acc[q][p][0] + v2q.x);
                    pk.y = f2bf(acc[q][p][1] + v2q.y);
                    pk.z = f2bf(acc[q][p][2] + v2q.z);
                    pk.w = f2bf(acc[q][p][3] + v2q.w);
                    *(ushort4*)(ldsT + (l << 9) + ((e0 << 1) ^ ((l & 7) << 4))) = pk;
                }
            }
        }
        barrier_lgkm();   // T' visible

        // ================= phase B: D[m][l] = x2 @ T'^T  (M=m, N=l, K=e), pipelined ==
#pragma unroll
        for (int q = 0; q < 4; ++q) { acc[q][0] = fz; acc[q][1] = fz; }
        {
            bf16x8 amC[4], amN[4], tfC[2], tfN[2];
#pragma unroll
            for (int q = 0; q < 4; ++q)
                amC[q] = *(const bf16x8*)(x2p + ((((wm << 2) + q) << 3) << 9) + (lane << 3));
#pragma unroll
            for (int p = 0; p < 2; ++p) {
                int l = (wl << 5) + (p << 4) + lrow;
                tfC[p] = *(const bf16x8*)(ldsT + (l << 9) + ((lk8 << 1) ^ ((l & 7) << 4)));
            }
#pragma unroll
            for (int et = 0; et < 8; ++et) {
                if (et < 7) {
                    int e = ((et + 1) << 5) + lk8;
#pragma unroll
                    for (int q = 0; q < 4; ++q)
                        amN[q] = *(const bf16x8*)(x2p + (((((wm << 2) + q) << 3) + et + 1) << 9) + (lane << 3));
#pragma unroll
                    for (int p = 0; p < 2; ++p) {
                        int l = (wl << 5) + (p << 4) + lrow;
                        tfN[p] = *(const bf16x8*)(ldsT + (l << 9) + ((e << 1) ^ ((l & 7) << 4)));
                    }
                }
#pragma unroll
                for (int p = 0; p < 2; ++p)
#pragma unroll
                    for (int q = 0; q < 4; ++q)
                        acc[q][p] = __builtin_amdgcn_mfma_f32_16x16x32_bf16(amC[q], tfC[p], acc[q][p], 0, 0, 0);
#pragma unroll
                for (int q = 0; q < 4; ++q) amC[q] = amN[q];
#pragma unroll
                for (int p = 0; p < 2; ++p) tfC[p] = tfN[p];
            }
        }
        barrier_lgkm();   // B's ldsT reads done -> safe to overwrite as f32 chunks

        // ================= epilogue: +r1, relu; FULL-ROW stores (lgkm-only bars) =====
        {
            float* outp = out + (((long)(b * NK + k)) << 16) + ((long)(lq << 6) << 8);
#pragma unroll
            for (int c = 0; c < 2; ++c) {
                if (wl == c) {
#pragma unroll
                    for (int q = 0; q < 4; ++q) {
                        int m0 = (wm << 6) + (q << 4) + j4;
#pragma unroll
                        for (int p = 0; p < 2; ++p) {
                            int row = (p << 4) + lrow;              // 0..31 within chunk
                            float rb = r1s[ki][(c << 5) + row];
                            f32x4 v;
                            v[0] = acc[q][p][0] + rb;
                            v[1] = acc[q][p][1] + rb;
                            v[2] = acc[q][p][2] + rb;
                            v[3] = acc[q][p][3] + rb;
                            v[0] = v[0] > 0.f ? v[0] : 0.f;
                            v[1] = v[1] > 0.f ? v[1] : 0.f;
                            v[2] = v[2] > 0.f ? v[2] : 0.f;
                            v[3] = v[3] > 0.f ? v[3] : 0.f;
                            *(f32x4*)(ldsT + (row << 10) + ((m0 << 2) ^ ((row & 7) << 4))) = v;
                        }
                    }
                }
                barrier_lgkm();
                // stream chunk: 32 rows x 1KB; each wave-iter writes ONE FULL ROW
#pragma unroll
                for (int it = 0; it < 4; ++it) {
                    int g = (it << 9) + tid;
                    int row = g >> 6;       // 0..31
                    int c4  = g & 63;       // 16B block within 1KB row
                    f32x4 v = *(const f32x4*)(ldsT + (row << 10) + ((c4 << 4) ^ ((row & 7) << 4)));
                    *(f32x4*)(outp + ((long)((c << 5) + row) << 8) + (c4 << 2)) = v;
                }
                if (c == 0) barrier_lgkm();
            }
        }
        // no trailing barrier: next k's A reads only ldsA/global; this k's stores
        // drain progressively under next k's 512 MFMAs.
    }
}

extern "C" void kernel_launch(void* const* d_in, const int* in_sizes, int n_in,
                              void* d_out, int out_size, void* d_ws, size_t ws_size,
                              hipStream_t stream) {
    const float* x1 = (const float*)d_in[0];
    const float* x2 = (const float*)d_in[1];
    const float* W  = (const float*)d_in[2];
    const float* V  = (const float*)d_in[3];
    const float* bb = (const float*)d_in[4];
    float* out = (float*)d_out;

    char* ws = (char*)d_ws;
    u16*   x1f  = (u16*)(ws);                               // 2 MiB
    u16*   x2f  = (u16*)(ws + (2l << 20));                  // 2 MiB
    u16*   Wtf  = (u16*)(ws + (4l << 20));                  // 4 MiB

    hipLaunchKernelGGL(prep_kernel, dim3(2304), dim3(256), 0, stream,
                       x1, x2, W, x1f, x2f, Wtf);
    hipLaunchKernelGGL(ntn_main, dim3(512), dim3(512), 0, stream,
                       x1f, x2f, Wtf, V, bb, out);
}